// Round 1
// baseline (2207.192 us; speedup 1.0000x reference)
//
#include <hip/hip_runtime.h>
#include <hip/hip_bf16.h>
#include <math.h>

#define NB    16
#define NPC   4096        // points per cloud
#define MPC   1024        // clusters per cloud
#define PTOT  65536
#define NCLU  16384
#define KNN_  16
#define CIN   64
#define COUT_ 128
#define CAUX_ 32

// out offsets (float elements), outputs concatenated in reference return order
#define OFF_XOUT   0
#define OFF_SUBPOS (NCLU*COUT_)               // 2097152
#define OFF_SUBB   (OFF_SUBPOS + NCLU*3)      // 2146304
#define OFF_AUX    (OFF_SUBB + NCLU)          // 2162688
#define OFF_IDCL   (OFF_AUX + NCLU*CAUX_)     // 2686976

// ws offsets (bytes)
#define WS_H        0
#define WS_CENTERS  (PTOT*COUT_*4)            // 33554432  (h: P x 128 f32)
#define WS_NN       (WS_CENTERS + NCLU*16)    // centers: float4 per cluster
#define WS_STATS    (WS_NN + NCLU*KNN_*4)     // nn ids
#define WS_SS       (WS_STATS + 256*4)        // sum[128], sumsq[128]
#define WS_NEED     (WS_SS + 256*4)           // scale[128], shift[128]

// ---------------- FPS: one block per cloud, 1023 sequential argmax steps ----
__global__ __launch_bounds__(1024) void fps_kernel(const float* __restrict__ pos,
                                                   float4* __restrict__ centers,
                                                   float* __restrict__ out)
{
  #pragma clang fp contract(off)
  __shared__ float lx[NPC], ly[NPC], lz[NPC];
  __shared__ float rv[16];
  __shared__ int   ri[16];
  __shared__ int   sel_l[MPC];
  __shared__ int   ssel;
  const int b = blockIdx.x;
  const int t = threadIdx.x;
  const float* pb = pos + (size_t)b * NPC * 3;
  for (int i = t; i < NPC; i += 1024) {
    lx[i] = pb[3*i+0]; ly[i] = pb[3*i+1]; lz[i] = pb[3*i+2];
  }
  __syncthreads();
  float px[4], py[4], pz[4], mind[4];
  const float x0 = lx[0], y0 = ly[0], z0 = lz[0];
  float bv = -1.0f; int bi = 0;
  #pragma unroll
  for (int j = 0; j < 4; ++j) {
    const int idx = t*4 + j;
    px[j] = lx[idx]; py[j] = ly[idx]; pz[j] = lz[idx];
    float dx = px[j]-x0, dy = py[j]-y0, dz = pz[j]-z0;
    float d = (dx*dx + dy*dy) + dz*dz;   // no-FMA: matches numpy rounding
    mind[j] = d;
    if (d > bv) { bv = d; bi = idx; }
  }
  if (t == 0) sel_l[0] = 0;
  const int lane = t & 63;
  const int wid  = t >> 6;
  for (int s = 1; s < MPC; ++s) {
    // wave-level argmax (max value, ties -> min index)
    float v = bv; int vi = bi;
    #pragma unroll
    for (int off = 32; off > 0; off >>= 1) {
      float ov = __shfl_xor(v, off, 64);
      int   oi = __shfl_xor(vi, off, 64);
      if (ov > v || (ov == v && oi < vi)) { v = ov; vi = oi; }
    }
    if (lane == 0) { rv[wid] = v; ri[wid] = vi; }
    __syncthreads();
    if (t < 64) {
      float v2 = (lane < 16) ? rv[lane] : -2.0f;
      int   i2 = (lane < 16) ? ri[lane] : 0x7fffffff;
      #pragma unroll
      for (int off = 8; off > 0; off >>= 1) {
        float ov = __shfl_xor(v2, off, 64);
        int   oi = __shfl_xor(i2, off, 64);
        if (ov > v2 || (ov == v2 && oi < i2)) { v2 = ov; i2 = oi; }
      }
      if (lane == 0) { ssel = i2; sel_l[s] = i2; }
    }
    __syncthreads();
    const int sel = ssel;
    const float sx = lx[sel], sy = ly[sel], sz = lz[sel];
    bv = -1.0f; bi = 0;
    #pragma unroll
    for (int j = 0; j < 4; ++j) {
      float dx = px[j]-sx, dy = py[j]-sy, dz = pz[j]-sz;
      float d = (dx*dx + dy*dy) + dz*dz;
      float m = fminf(mind[j], d);
      mind[j] = m;
      if (m > bv) { bv = m; bi = t*4 + j; }
    }
  }
  __syncthreads();
  {
    const int c  = t;                    // exactly one cluster per thread
    const int il = sel_l[c];
    const int cl = b*MPC + c;
    const float X = lx[il], Y = ly[il], Z = lz[il];
    centers[cl] = make_float4(X, Y, Z, 0.0f);
    out[OFF_SUBPOS + cl*3 + 0] = X;
    out[OFF_SUBPOS + cl*3 + 1] = Y;
    out[OFF_SUBPOS + cl*3 + 2] = Z;
    out[OFF_SUBB + cl] = (float)b;
    out[OFF_IDCL + cl] = (float)(b*NPC + il);
  }
}

// ---------------- GEMM h = x@W + b, plus BN sum/sumsq accumulation ----------
__global__ __launch_bounds__(256) void gemm_kernel(const float* __restrict__ x,
                                                   const float* __restrict__ W,
                                                   const float* __restrict__ bias,
                                                   float* __restrict__ h,
                                                   float* __restrict__ stats)
{
  __shared__ float xT[64][68];     // [k][row], padded to kill bank conflicts
  __shared__ float Wl[64][128];
  __shared__ float bsum[128], bsq[128];
  const int t = threadIdx.x;
  const int blk = blockIdx.x;
  const int row0 = blk * 64;
  if (t < 128) { bsum[t] = 0.0f; bsq[t] = 0.0f; }
  #pragma unroll
  for (int i = 0; i < 16; ++i) {
    const int idx = t + i*256;
    xT[idx & 63][idx >> 6] = x[(size_t)row0*64 + idx];
  }
  #pragma unroll
  for (int i = 0; i < 32; ++i) {
    const int idx = t + i*256;
    ((float*)Wl)[idx] = W[idx];
  }
  __syncthreads();
  const int tx = t & 15, ty = t >> 4;   // 16x16 threads, 4 rows x 8 cols each
  float acc[4][8] = {};
  #pragma unroll 8
  for (int k = 0; k < 64; ++k) {
    const float4 a  = *(const float4*)&xT[k][ty*4];
    const float4 b0 = *(const float4*)&Wl[k][tx*8];
    const float4 b1 = *(const float4*)&Wl[k][tx*8+4];
    const float av[4] = {a.x, a.y, a.z, a.w};
    const float bw[8] = {b0.x,b0.y,b0.z,b0.w,b1.x,b1.y,b1.z,b1.w};
    #pragma unroll
    for (int i2 = 0; i2 < 4; ++i2)
      #pragma unroll
      for (int e = 0; e < 8; ++e)
        acc[i2][e] += av[i2] * bw[e];
  }
  const int c0 = tx*8;
  float bb[8];
  #pragma unroll
  for (int e = 0; e < 8; ++e) bb[e] = bias[c0+e];
  float s8[8] = {}, q8[8] = {};
  #pragma unroll
  for (int i2 = 0; i2 < 4; ++i2) {
    float vv[8];
    #pragma unroll
    for (int e = 0; e < 8; ++e) {
      float v = acc[i2][e] + bb[e];
      vv[e] = v; s8[e] += v; q8[e] += v*v;
    }
    const int r = row0 + ty*4 + i2;
    float4* dst = (float4*)&h[(size_t)r*128 + c0];
    dst[0] = make_float4(vv[0], vv[1], vv[2], vv[3]);
    dst[1] = make_float4(vv[4], vv[5], vv[6], vv[7]);
  }
  #pragma unroll
  for (int e = 0; e < 8; ++e) {
    atomicAdd(&bsum[c0+e], s8[e]);
    atomicAdd(&bsq[c0+e],  q8[e]);
  }
  __syncthreads();
  if (t < 128) {
    atomicAdd(&stats[t],      bsum[t]);
    atomicAdd(&stats[128+t],  bsq[t]);
  }
}

// ---------------- BN finalize: scale/shift per column -----------------------
__global__ __launch_bounds__(128) void bn_finalize(const float* __restrict__ stats,
                                                   const float* __restrict__ gamma,
                                                   const float* __restrict__ beta,
                                                   float* __restrict__ ss)
{
  const int t = threadIdx.x;
  const float inv = 1.0f / 65536.0f;
  const float mu  = stats[t] * inv;
  const float var = stats[128+t] * inv - mu*mu;
  const float sc  = gamma[t] * rsqrtf(var + 1e-5f);
  ss[t]      = sc;
  ss[128+t]  = beta[t] - mu*sc;
}

// ---------------- kNN: 8 threads per center, exact (d2, idx) top-16 ---------
__global__ __launch_bounds__(256) void knn_kernel(const float* __restrict__ pos,
                                                  const float4* __restrict__ centers,
                                                  int* __restrict__ nn)
{
  #pragma clang fp contract(off)
  __shared__ float4 lp[NPC];        // 64KB; reused as candidate scratch after scan
  const int blk = blockIdx.x;       // 512 blocks; 32 per cloud
  const int b   = blk >> 5;
  const int c0  = (blk & 31) * 32;  // first local center of this block
  const int t   = threadIdx.x;
  const int q   = t & 7;            // subset
  const int cc  = t >> 3;           // center within block, 0..31
  const float* pb = pos + (size_t)b * NPC * 3;
  for (int i = t; i < NPC; i += 256)
    lp[i] = make_float4(pb[3*i], pb[3*i+1], pb[3*i+2], 0.0f);
  __syncthreads();
  const int cg = b*MPC + c0 + cc;   // global cluster index
  const float4 C = centers[cg];
  float dsl[16]; int isl[16];
  #pragma unroll
  for (int k = 0; k < 16; ++k) { dsl[k] = INFINITY; isl[k] = 0x7fffffff; }
  float wv = INFINITY; int wi = 0x7fffffff; int wslot = 0;
  for (int jj = 0; jj < NPC/8; ++jj) {
    const int j = jj*8 + q;         // strictly increasing within thread
    const float4 p = lp[j];
    float dx = C.x - p.x, dy = C.y - p.y, dz = C.z - p.z;
    float d2 = (dx*dx + dy*dy) + dz*dz;   // no-FMA
    if (d2 < wv || (d2 == wv && j < wi)) {
      #pragma unroll
      for (int k = 0; k < 16; ++k) if (k == wslot) { dsl[k] = d2; isl[k] = j; }
      wv = dsl[0]; wi = isl[0]; wslot = 0;
      #pragma unroll
      for (int k = 1; k < 16; ++k)
        if (dsl[k] > wv || (dsl[k] == wv && isl[k] > wi)) { wv = dsl[k]; wi = isl[k]; wslot = k; }
    }
  }
  __syncthreads();                  // pos data no longer needed
  float* cd = (float*)lp;           // [32 centers][8 subsets][16]
  int*   ci = ((int*)lp) + 32*8*16;
  #pragma unroll
  for (int k = 0; k < 16; ++k) {
    cd[(cc*8 + q)*16 + k] = dsl[k];
    ci[(cc*8 + q)*16 + k] = isl[k];
  }
  __syncthreads();
  if (q == 0) {
    // merge 128 candidates lexicographically by (d2, idx) -> exact top-16 set
    float md[16]; int mi[16];
    #pragma unroll
    for (int k = 0; k < 16; ++k) { md[k] = INFINITY; mi[k] = 0x7fffffff; }
    float w2 = INFINITY; int w2i = 0x7fffffff; int w2s = 0;
    for (int e = 0; e < 128; ++e) {
      const float d  = cd[cc*128 + e];
      const int   id = ci[cc*128 + e];
      if (d < w2 || (d == w2 && id < w2i)) {
        #pragma unroll
        for (int k = 0; k < 16; ++k) if (k == w2s) { md[k] = d; mi[k] = id; }
        w2 = md[0]; w2i = mi[0]; w2s = 0;
        #pragma unroll
        for (int k = 1; k < 16; ++k)
          if (md[k] > w2 || (md[k] == w2 && mi[k] > w2i)) { w2 = md[k]; w2i = mi[k]; w2s = k; }
      }
    }
    #pragma unroll
    for (int k = 0; k < 16; ++k) nn[cg*16 + k] = b*NPC + mi[k];
  }
}

// ---------------- Pool: per-cluster max(relu(bn(h))) + mean(aux) ------------
__global__ __launch_bounds__(128) void pool_kernel(const float* __restrict__ h,
                                                   const float* __restrict__ aux,
                                                   const int* __restrict__ nn,
                                                   const float* __restrict__ ss,
                                                   float* __restrict__ out)
{
  __shared__ int ids[16];
  const int cl = blockIdx.x;
  const int t  = threadIdx.x;
  if (t < 16) ids[t] = nn[cl*16 + t];
  __syncthreads();
  const float sc = ss[t], sh = ss[128+t];
  float mv = 0.0f;                        // relu output >= 0, so 0 == -inf here
  #pragma unroll
  for (int k = 0; k < 16; ++k) {
    const float hv = h[(size_t)ids[k]*128 + t];
    mv = fmaxf(mv, fmaxf(sc*hv + sh, 0.0f));
  }
  out[OFF_XOUT + (size_t)cl*128 + t] = mv;
  if (t < 32) {
    float s = 0.0f;
    #pragma unroll
    for (int k = 0; k < 16; ++k) s += aux[(size_t)ids[k]*32 + t];
    out[OFF_AUX + (size_t)cl*32 + t] = s * (1.0f/16.0f);
  }
}

extern "C" void kernel_launch(void* const* d_in, const int* in_sizes, int n_in,
                              void* d_out, int out_size, void* d_ws, size_t ws_size,
                              hipStream_t stream)
{
  const float* x     = (const float*)d_in[0];
  const float* pos   = (const float*)d_in[1];
  // d_in[2] = batch (int32) — clouds are equal-size, derived analytically
  const float* aux   = (const float*)d_in[3];
  const float* W     = (const float*)d_in[4];
  const float* bias  = (const float*)d_in[5];
  const float* gamma = (const float*)d_in[6];
  const float* beta  = (const float*)d_in[7];
  float* out = (float*)d_out;
  char*  ws  = (char*)d_ws;
  if (ws_size < (size_t)WS_NEED) return;   // insufficient scratch: bail cleanly

  float*  h       = (float*)(ws + WS_H);
  float4* centers = (float4*)(ws + WS_CENTERS);
  int*    nn      = (int*)(ws + WS_NN);
  float*  stats   = (float*)(ws + WS_STATS);
  float*  ss      = (float*)(ws + WS_SS);

  hipMemsetAsync(stats, 0, 256*4, stream);  // BN accumulators: zero every call
  hipLaunchKernelGGL(fps_kernel,  dim3(NB),       dim3(1024), 0, stream, pos, centers, out);
  hipLaunchKernelGGL(gemm_kernel, dim3(PTOT/64),  dim3(256),  0, stream, x, W, bias, h, stats);
  hipLaunchKernelGGL(bn_finalize, dim3(1),        dim3(128),  0, stream, stats, gamma, beta, ss);
  hipLaunchKernelGGL(knn_kernel,  dim3(512),      dim3(256),  0, stream, pos, centers, nn);
  hipLaunchKernelGGL(pool_kernel, dim3(NCLU),     dim3(128),  0, stream, h, aux, nn, ss, out);
}